// Round 9
// baseline (199.901 us; speedup 1.0000x reference)
//
#include <hip/hip_runtime.h>
#include <hip/hip_bf16.h>

// Problem constants (B, C, T, H, KC, WIN) = (4, 512, 1024, 8, 64, 4)
#define Bdim 4
#define Cdim 512
#define Tdim 1024
#define Hn   8
#define KCd  64

typedef __attribute__((ext_vector_type(8))) short bf16x8;   // 8 bf16 = 4 VGPR
typedef __attribute__((ext_vector_type(4))) float f32x4;    // MFMA C/D

__device__ __forceinline__ unsigned short f32_bf16_rne(float f) {
    unsigned u = __float_as_uint(f);
    u += 0x7FFFu + ((u >> 16) & 1u);
    return (unsigned short)(u >> 16);
}
__device__ __forceinline__ float bf16_f32(unsigned short h) {
    return __uint_as_float(((unsigned)h) << 16);
}
__device__ __forceinline__ void split8(const float* f, bf16x8& h8, bf16x8& l8) {
    #pragma unroll
    for (int e = 0; e < 8; ++e) {
        const unsigned short hh = f32_bf16_rne(f[e]);
        h8[e] = (short)hh;
        l8[e] = (short)f32_bf16_rne(f[e] - bf16_f32(hh));
    }
}

// LDS 64x64 tile XOR swizzle (only for attention's P round-trip)
__device__ __forceinline__ int sw(int row, int col) {
    return (row << 6) + ((((col >> 3) ^ (row & 7)) << 3) | (col & 7));
}
__device__ __forceinline__ bf16x8 fragld(const unsigned short* a, int row, int kstep, int quad) {
    return *(const bf16x8*)&a[(row << 6) + ((((kstep << 2) | quad) ^ (row & 7)) << 3)];
}

// ---------------------------------------------------------------------------
// FRAG-MAJOR plane layouts (all hi/lo pre-split):
//  A-plane (weights, stacked [wq;wk;wv;wo] = 2048 rows x 512 k):
//    [mtile16:128][ktile:16][lane:64][e:8]; elem(m,k): lane=(k>>3&3)*16+(m&15), e=k&7
//  B-plane (X / ctx: n=time 1024, k=channels 512, per batch):
//    [b][ntile16:64][ktile:16][lane:64][e:8]; elem(n,k): lane=(k>>3&3)*16+(n&15), e=k&7
//  Attention planes (per (b,h), 16 time-tiles of 64x64, as in R8):
//    row-type (Q,K): g=(t>>4)*2+(c>>5), lane=((c>>3)&3)*16+(t&15), e=c&7
//    col-type (V):   g=(c>>4)*2+(t>>5), lane=((t>>3)&3)*16+(c&15), e=t&7
// Every MFMA fragment = contiguous, lane-ordered 1 KB -> coalesced dwordx4.
// ---------------------------------------------------------------------------

// ---------------------------------------------------------------------------
// prep: one-time fp32 -> hi/lo bf16 split into frag-major planes.
// 6144 wave-tasks: 2048 W-tasks (mtile16, kt) + 4096 X-tasks (b, ntile16, kt).
// ---------------------------------------------------------------------------
__global__ __launch_bounds__(256) void prep_kernel(
    const float* __restrict__ wq, const float* __restrict__ wk,
    const float* __restrict__ wv, const float* __restrict__ wo,
    const float* __restrict__ x,
    unsigned short* __restrict__ WAhi, unsigned short* __restrict__ WAlo,
    unsigned short* __restrict__ XBhi, unsigned short* __restrict__ XBlo)
{
    const int w = threadIdx.x >> 6, lane = threadIdx.x & 63;
    const int l15 = lane & 15, quad = lane >> 4;
    const int task = blockIdx.x * 4 + w;

    if (task < 2048) {
        const int mtile = task >> 4, kt = task & 15;
        const int sel = mtile >> 5;
        const float* W = sel == 0 ? wq : (sel == 1 ? wk : (sel == 2 ? wv : wo));
        const int row = (mtile & 31) * 16 + l15;
        const float* p = W + (size_t)row * Cdim + kt * 32 + quad * 8;
        float f[8];
        *(float4*)&f[0] = *(const float4*)p;
        *(float4*)&f[4] = *(const float4*)(p + 4);
        bf16x8 h8, l8;
        split8(f, h8, l8);
        const size_t base = (size_t)task * 512 + lane * 8;
        *(bf16x8*)(WAhi + base) = h8;
        *(bf16x8*)(WAlo + base) = l8;
    } else {
        const int t2 = task - 2048;
        const int b = t2 >> 10, ntile = (t2 >> 4) & 63, kt = t2 & 15;
        const float* Xb = x + (size_t)b * Cdim * Tdim;
        const int n = ntile * 16 + l15;
        const int k0 = kt * 32 + quad * 8;
        float f[8];
        #pragma unroll
        for (int e = 0; e < 8; ++e) f[e] = Xb[(size_t)(k0 + e) * Tdim + n];
        bf16x8 h8, l8;
        split8(f, h8, l8);
        const size_t base = (size_t)t2 * 512 + lane * 8;
        *(bf16x8*)(XBhi + base) = h8;
        *(bf16x8*)(XBlo + base) = l8;
    }
}

// ---------------------------------------------------------------------------
// Barrier-free bf16x3 MFMA GEMM, zero LDS. One wave = 64m x 64n x 512k.
// A/B frags stream directly from frag-major global planes (coalesced dwordx4),
// double-buffered across kt. mode 0: QKV (A rows 0..1535) -> attn planes.
// mode 1: out-proj (A rows 1536..2047 = Wo) -> natural fp32 out.
// XCD-clustered decode: blocks sharing a (b, n64) column land on one XCD.
// ---------------------------------------------------------------------------
__global__ __launch_bounds__(256) void gemm_mfma(
    int mode,
    const unsigned short* __restrict__ Ahi, const unsigned short* __restrict__ Alo,
    const unsigned short* __restrict__ Bhi, const unsigned short* __restrict__ Blo,
    const float* __restrict__ b0, const float* __restrict__ b1, const float* __restrict__ b2,
    unsigned short* __restrict__ qhi, unsigned short* __restrict__ qlo,
    unsigned short* __restrict__ khi, unsigned short* __restrict__ klo,
    unsigned short* __restrict__ vhi, unsigned short* __restrict__ vlo,
    float* __restrict__ ofp)
{
    const int tid = threadIdx.x;
    const int w = tid >> 6, lane = tid & 63;
    const int l15 = lane & 15, quad = lane >> 4;
    const int lo8 = lane << 3;

    int b, n64, m64, mtb, sel;
    {
        const int id = blockIdx.x;
        const int xcd = id & 7, slot = id >> 3;
        if (mode == 0) {                 // 384 blocks: 48/XCD = 8 cols x 6 mgroups
            const int col = xcd * 8 + slot / 6;
            const int mg = slot % 6;
            b = col >> 4; n64 = col & 15;
            m64 = mg * 4 + w;            // 0..23 (stacked q/k/v)
            mtb = m64 * 4;
            sel = m64 >> 3;
        } else {                          // 128 blocks: 16/XCD = 8 cols x 2 mgroups
            const int col = xcd * 8 + (slot >> 1);
            const int mg = slot & 1;
            b = col >> 4; n64 = col & 15;
            m64 = mg * 4 + w;            // 0..7 (local)
            mtb = 96 + m64 * 4;          // Wo rows
            sel = 0;
        }
    }
    const int ntb = b * 64 + n64 * 4;

    f32x4 acc[4][4];
    #pragma unroll
    for (int i = 0; i < 4; ++i)
        #pragma unroll
        for (int j = 0; j < 4; ++j) acc[i][j] = (f32x4){0.f, 0.f, 0.f, 0.f};

    bf16x8 Ah[2][4], Al[2][4], Bh[2][4], Bl[2][4];

    // load kt=0
    #pragma unroll
    for (int mt = 0; mt < 4; ++mt) {
        const size_t o = (size_t)(mtb + mt) * 8192 + lo8;
        Ah[0][mt] = *(const bf16x8*)(Ahi + o);
        Al[0][mt] = *(const bf16x8*)(Alo + o);
    }
    #pragma unroll
    for (int nt = 0; nt < 4; ++nt) {
        const size_t o = (size_t)(ntb + nt) * 8192 + lo8;
        Bh[0][nt] = *(const bf16x8*)(Bhi + o);
        Bl[0][nt] = *(const bf16x8*)(Blo + o);
    }

    for (int kt = 0; kt < 16; ++kt) {
        const int cur = kt & 1, nxt = cur ^ 1;
        if (kt < 15) {
            const int kn = (kt + 1) * 512;
            #pragma unroll
            for (int mt = 0; mt < 4; ++mt) {
                const size_t o = (size_t)(mtb + mt) * 8192 + kn + lo8;
                Ah[nxt][mt] = *(const bf16x8*)(Ahi + o);
                Al[nxt][mt] = *(const bf16x8*)(Alo + o);
            }
            #pragma unroll
            for (int nt = 0; nt < 4; ++nt) {
                const size_t o = (size_t)(ntb + nt) * 8192 + kn + lo8;
                Bh[nxt][nt] = *(const bf16x8*)(Bhi + o);
                Bl[nxt][nt] = *(const bf16x8*)(Blo + o);
            }
        }
        #pragma unroll
        for (int mt = 0; mt < 4; ++mt)
            #pragma unroll
            for (int nt = 0; nt < 4; ++nt) {
                f32x4 c = acc[mt][nt];
                c = __builtin_amdgcn_mfma_f32_16x16x32_bf16(Ah[cur][mt], Bh[cur][nt], c, 0, 0, 0);
                c = __builtin_amdgcn_mfma_f32_16x16x32_bf16(Ah[cur][mt], Bl[cur][nt], c, 0, 0, 0);
                c = __builtin_amdgcn_mfma_f32_16x16x32_bf16(Al[cur][mt], Bh[cur][nt], c, 0, 0, 0);
                acc[mt][nt] = c;
            }
    }

    // ---- epilogue: D[m = quad*4+r][n = l15] ----
    if (mode == 1) {
        // natural fp32: out[b][m][t] += bias
        float* Ob = ofp + (size_t)b * Cdim * Tdim;
        #pragma unroll
        for (int mt = 0; mt < 4; ++mt) {
            const int m = m64 * 64 + mt * 16 + quad * 4;
            float bb[4];
            #pragma unroll
            for (int r = 0; r < 4; ++r) bb[r] = b0[m + r];
            #pragma unroll
            for (int nt = 0; nt < 4; ++nt) {
                const int t = n64 * 64 + nt * 16 + l15;
                #pragma unroll
                for (int r = 0; r < 4; ++r)
                    Ob[(size_t)(m + r) * Tdim + t] = acc[mt][nt][r] + bb[r];
            }
        }
    } else if (sel < 2) {
        // Q/K row-type attn planes
        const float* Bv = sel == 0 ? b0 : b1;
        unsigned short* ph = sel == 0 ? qhi : khi;
        unsigned short* pl = sel == 0 ? qlo : klo;
        #pragma unroll
        for (int mt = 0; mt < 4; ++mt) {
            const int mv = m64 * 64 + mt * 16 + quad * 4;     // stacked
            const int head = (mv >> 6) & 7;
            const int c0 = mt * 16 + quad * 4;                // channel-in-head base
            float bb[4];
            #pragma unroll
            for (int r = 0; r < 4; ++r) bb[r] = Bv[(mv & 511) + r];
            const int lane_out = (((c0 >> 3) & 3) << 4) + l15;
            const int e0 = c0 & 7;                            // 0 or 4
            const size_t tbase = (((size_t)(b * Hn + head) * 16 + n64) << 12);
            #pragma unroll
            for (int nt = 0; nt < 4; ++nt) {
                const int g = nt * 2 + (mt >> 1);
                const size_t off = tbase + g * 512 + lane_out * 8 + e0;
                ushort4 h4, l4;
                #pragma unroll
                for (int r = 0; r < 4; ++r) {
                    const float v = acc[mt][nt][r] + bb[r];
                    const unsigned short hh = f32_bf16_rne(v);
                    ((unsigned short*)&h4)[r] = hh;
                    ((unsigned short*)&l4)[r] = f32_bf16_rne(v - bf16_f32(hh));
                }
                *(ushort4*)(ph + off) = h4;
                *(ushort4*)(pl + off) = l4;
            }
        }
    } else {
        // V col-type attn planes (scatter ushort stores)
        #pragma unroll
        for (int mt = 0; mt < 4; ++mt) {
            const int mv = m64 * 64 + mt * 16 + quad * 4;
            const int head = (mv >> 6) & 7;
            float bb[4];
            #pragma unroll
            for (int r = 0; r < 4; ++r) bb[r] = b2[(mv & 511) + r];
            const size_t tbase = (((size_t)(b * Hn + head) * 16 + n64) << 12);
            #pragma unroll
            for (int nt = 0; nt < 4; ++nt) {
                const int tl = nt * 16 + l15;
                const int g = mt * 2 + (tl >> 5);
                const int lv0 = (((tl >> 3) & 3) << 4) + quad * 4;   // + r
                const int e = tl & 7;
                #pragma unroll
                for (int r = 0; r < 4; ++r) {
                    const float v = acc[mt][nt][r] + bb[r];
                    const unsigned short hh = f32_bf16_rne(v);
                    const size_t off = tbase + g * 512 + (size_t)(lv0 + r) * 8 + e;
                    vhi[off] = hh;
                    vlo[off] = f32_bf16_rne(v - bf16_f32(hh));
                }
            }
        }
    }
}

// ---------------------------------------------------------------------------
// Barrier-free MFMA flash attention (R8 structure). Epilogue now writes ctx
// directly as B-operand frag-major hi/lo planes for the out-projection.
// ---------------------------------------------------------------------------
__global__ __launch_bounds__(256) void attn_mfma(
    const unsigned short* __restrict__ qhi, const unsigned short* __restrict__ qlo,
    const unsigned short* __restrict__ khi, const unsigned short* __restrict__ klo,
    const unsigned short* __restrict__ vhi, const unsigned short* __restrict__ vlo,
    const float* __restrict__ ek,   // [9,64]
    const float* __restrict__ ev,   // [9,64]
    unsigned short* __restrict__ cxhi, unsigned short* __restrict__ cxlo)
{
    __shared__ alignas(16) unsigned short psh[4096], psl[4096];
    __shared__ float rk[576];
    __shared__ float evs[576];

    const int tid = threadIdx.x;
    int it, h, b;
    {
        const int n = blockIdx.x;
        const int xcd = n & 7, slot = n >> 3;
        const int pair = (xcd << 2) | (slot >> 4);
        it = slot & 15;
        b = pair >> 3;
        h = pair & 7;
    }
    const int i0 = it * 64;
    const int lane = tid & 63, w = tid >> 6;
    const int l15 = lane & 15, quad = lane >> 4;
    const int m_blk = w * 16 + l15;
    const int lo8 = lane << 3;

    const size_t bh16 = (size_t)(b * Hn + h) * 16;

    bf16x8 qfh[2], qfl[2];
    {
        const unsigned short* qth = qhi + ((bh16 + it) << 12);
        const unsigned short* qtl = qlo + ((bh16 + it) << 12);
        #pragma unroll
        for (int ks = 0; ks < 2; ++ks) {
            qfh[ks] = *(const bf16x8*)(qth + (((w << 1) | ks) << 9) + lo8);
            qfl[ks] = *(const bf16x8*)(qtl + (((w << 1) | ks) << 9) + lo8);
        }
    }

    bf16x8 ekh[2], ekl[2];
    #pragma unroll
    for (int ks = 0; ks < 2; ++ks) {
        #pragma unroll
        for (int j = 0; j < 8; ++j) { ekh[ks][j] = 0; ekl[ks][j] = 0; }
        if (l15 < 9) {
            #pragma unroll
            for (int j = 0; j < 8; ++j) {
                const float v = ek[l15 * 64 + ks * 32 + quad * 8 + j];
                const unsigned short hh = f32_bf16_rne(v);
                ekh[ks][j] = (short)hh;
                ekl[ks][j] = (short)f32_bf16_rne(v - bf16_f32(hh));
            }
        }
    }

    {
        f32x4 rkD = (f32x4){0.f, 0.f, 0.f, 0.f};
        #pragma unroll
        for (int ks = 0; ks < 2; ++ks) {
            rkD = __builtin_amdgcn_mfma_f32_16x16x32_bf16(qfh[ks], ekh[ks], rkD, 0, 0, 0);
            rkD = __builtin_amdgcn_mfma_f32_16x16x32_bf16(qfh[ks], ekl[ks], rkD, 0, 0, 0);
            rkD = __builtin_amdgcn_mfma_f32_16x16x32_bf16(qfl[ks], ekh[ks], rkD, 0, 0, 0);
        }
        if (l15 < 9) {
            #pragma unroll
            for (int r = 0; r < 4; ++r)
                rk[(w * 16 + quad * 4 + r) * 9 + l15] = rkD[r];
        }
    }
    for (int idx = tid; idx < 576; idx += 256) evs[idx] = ev[idx];
    __syncthreads();   // the ONLY barrier

    float m_run = -1e30f, l_run = 0.f;
    f32x4 Oc[4];
    #pragma unroll
    for (int ct = 0; ct < 4; ++ct) Oc[ct] = (f32x4){0.f, 0.f, 0.f, 0.f};

    const unsigned short* kh0 = khi + (bh16 << 12);
    const unsigned short* kl0 = klo + (bh16 << 12);
    const unsigned short* vh0 = vhi + (bh16 << 12);
    const unsigned short* vl0 = vlo + (bh16 << 12);

    for (int t = 0; t < 16; ++t) {
        const int j0 = t << 6;
        const size_t tb = (size_t)t << 12;
        const unsigned short* kht = kh0 + tb;
        const unsigned short* klt = kl0 + tb;
        const unsigned short* vht = vh0 + tb;
        const unsigned short* vlt = vl0 + tb;

        bf16x8 vbh[2][4], vbl[2][4];
        #pragma unroll
        for (int ks = 0; ks < 2; ++ks)
            #pragma unroll
            for (int ct = 0; ct < 4; ++ct) {
                vbh[ks][ct] = *(const bf16x8*)(vht + (((ct << 1) | ks) << 9) + lo8);
                vbl[ks][ct] = *(const bf16x8*)(vlt + (((ct << 1) | ks) << 9) + lo8);
            }

        f32x4 Sc[4];
        #pragma unroll
        for (int jt = 0; jt < 4; ++jt) Sc[jt] = (f32x4){0.f, 0.f, 0.f, 0.f};
        #pragma unroll
        for (int ks = 0; ks < 2; ++ks) {
            bf16x8 ah[4], al[4];
            #pragma unroll
            for (int jt = 0; jt < 4; ++jt) {
                ah[jt] = *(const bf16x8*)(kht + (((jt << 1) | ks) << 9) + lo8);
                al[jt] = *(const bf16x8*)(klt + (((jt << 1) | ks) << 9) + lo8);
            }
            #pragma unroll
            for (int jt = 0; jt < 4; ++jt) {
                Sc[jt] = __builtin_amdgcn_mfma_f32_16x16x32_bf16(ah[jt], qfh[ks], Sc[jt], 0, 0, 0);
                Sc[jt] = __builtin_amdgcn_mfma_f32_16x16x32_bf16(ah[jt], qfl[ks], Sc[jt], 0, 0, 0);
                Sc[jt] = __builtin_amdgcn_mfma_f32_16x16x32_bf16(al[jt], qfh[ks], Sc[jt], 0, 0, 0);
            }
        }

        const int dt = j0 - i0;
        const bool diag = (dt >= -67 && dt <= 67);
        if (diag) {
            #pragma unroll
            for (int jt = 0; jt < 4; ++jt) {
                const int db = dt + jt * 16 + quad * 4 - m_blk;
                #pragma unroll
                for (int r = 0; r < 4; ++r) {
                    const int d = db + r;
                    if ((unsigned)(d + 4) <= 8u) Sc[jt][r] += rk[m_blk * 9 + d + 4];
                }
            }
        }

        float mt = -1e30f;
        #pragma unroll
        for (int jt = 0; jt < 4; ++jt)
            #pragma unroll
            for (int r = 0; r < 4; ++r) {
                Sc[jt][r] *= 0.125f;
                mt = fmaxf(mt, Sc[jt][r]);
            }
        mt = fmaxf(mt, __shfl_xor(mt, 16));
        mt = fmaxf(mt, __shfl_xor(mt, 32));
        const float mn = fmaxf(m_run, mt);
        const float alpha = __expf(m_run - mn);
        float rs = 0.f;
        #pragma unroll
        for (int jt = 0; jt < 4; ++jt)
            #pragma unroll
            for (int r = 0; r < 4; ++r) {
                const float e = __expf(Sc[jt][r] - mn);
                Sc[jt][r] = e;
                rs += e;
            }
        rs += __shfl_xor(rs, 16);
        rs += __shfl_xor(rs, 32);
        l_run = l_run * alpha + rs;
        m_run = mn;

        #pragma unroll
        for (int jt = 0; jt < 4; ++jt) {
            ushort4 ph, pl;
            ph.x = f32_bf16_rne(Sc[jt][0]); pl.x = f32_bf16_rne(Sc[jt][0] - bf16_f32(ph.x));
            ph.y = f32_bf16_rne(Sc[jt][1]); pl.y = f32_bf16_rne(Sc[jt][1] - bf16_f32(ph.y));
            ph.z = f32_bf16_rne(Sc[jt][2]); pl.z = f32_bf16_rne(Sc[jt][2] - bf16_f32(ph.z));
            ph.w = f32_bf16_rne(Sc[jt][3]); pl.w = f32_bf16_rne(Sc[jt][3] - bf16_f32(ph.w));
            const int o = sw(m_blk, jt * 16 + quad * 4);
            *(ushort4*)&psh[o] = ph;
            *(ushort4*)&psl[o] = pl;
        }
        // no barrier: intra-wave P rows only

        const float al0 = __shfl(alpha, quad * 4 + 0);
        const float al1 = __shfl(alpha, quad * 4 + 1);
        const float al2 = __shfl(alpha, quad * 4 + 2);
        const float al3 = __shfl(alpha, quad * 4 + 3);
        #pragma unroll
        for (int ct = 0; ct < 4; ++ct) {
            Oc[ct][0] *= al0; Oc[ct][1] *= al1; Oc[ct][2] *= al2; Oc[ct][3] *= al3;
        }
        #pragma unroll
        for (int ks = 0; ks < 2; ++ks) {
            bf16x8 pah = fragld(psh, m_blk, ks, quad);
            bf16x8 pal = fragld(psl, m_blk, ks, quad);
            #pragma unroll
            for (int ct = 0; ct < 4; ++ct) {
                Oc[ct] = __builtin_amdgcn_mfma_f32_16x16x32_bf16(pah, vbh[ks][ct], Oc[ct], 0, 0, 0);
                Oc[ct] = __builtin_amdgcn_mfma_f32_16x16x32_bf16(pah, vbl[ks][ct], Oc[ct], 0, 0, 0);
                Oc[ct] = __builtin_amdgcn_mfma_f32_16x16x32_bf16(pal, vbh[ks][ct], Oc[ct], 0, 0, 0);
            }
        }

        if (diag) {
            #pragma unroll
            for (int r = 0; r < 4; ++r) {
                const int mrow = w * 16 + quad * 4 + r;
                const int ig = i0 + mrow;
                #pragma unroll
                for (int e = 0; e < 9; ++e) {
                    const int jl = ig + e - 4 - j0;
                    if ((unsigned)jl < 64u) {
                        const int o = sw(mrow, jl);
                        const float p = bf16_f32(psh[o]) + bf16_f32(psl[o]);
                        #pragma unroll
                        for (int ct = 0; ct < 4; ++ct)
                            Oc[ct][r] += p * evs[e * 64 + ct * 16 + l15];
                    }
                }
            }
        }
    }

    // ---- epilogue: normalize, write ctx B-operand frag-major hi/lo planes ----
    const float rlv = 1.f / l_run;
    float rl[4];
    rl[0] = __shfl(rlv, quad * 4 + 0);
    rl[1] = __shfl(rlv, quad * 4 + 1);
    rl[2] = __shfl(rlv, quad * 4 + 2);
    rl[3] = __shfl(rlv, quad * 4 + 3);
    const int ntile16 = it * 4 + w;
    const int e = l15 & 7;
    #pragma unroll
    for (int ct = 0; ct < 4; ++ct) {
        const int cl = ct * 16 + l15;                    // channel within head
        const int ktc = h * 2 + (cl >> 5);
        const int lane_c = (((ct * 2 + (l15 >> 3)) & 3) << 4) + quad * 4;   // + r
        const size_t base = (((size_t)(b * 64 + ntile16)) * 16 + ktc) * 512;
        #pragma unroll
        for (int r = 0; r < 4; ++r) {
            const float v = Oc[ct][r] * rl[r];
            const unsigned short hh = f32_bf16_rne(v);
            const size_t off = base + (size_t)(lane_c + r) * 8 + e;
            cxhi[off] = hh;
            cxlo[off] = f32_bf16_rne(v - bf16_f32(hh));
        }
    }
}

// ---------------------------------------------------------------------------
extern "C" void kernel_launch(void* const* d_in, const int* in_sizes, int n_in,
                              void* d_out, int out_size, void* d_ws, size_t ws_size,
                              hipStream_t stream) {
    const float* x  = (const float*)d_in[0];
    const float* wq = (const float*)d_in[1];
    const float* bq = (const float*)d_in[2];
    const float* wk = (const float*)d_in[3];
    const float* bk = (const float*)d_in[4];
    const float* wv = (const float*)d_in[5];
    const float* bv = (const float*)d_in[6];
    const float* wo = (const float*)d_in[7];
    const float* bo = (const float*)d_in[8];
    const float* ek = (const float*)d_in[9];
    const float* ev = (const float*)d_in[10];
    float* out = (float*)d_out;

    const size_t PW = 2048u * 512u;          // 1,048,576 (stacked W elements)
    const size_t PX = 4u * 1024u * 512u;     // 2,097,152 (X / ctx / attn planes)
    unsigned short* WAhi = (unsigned short*)d_ws;
    unsigned short* WAlo = WAhi + PW;
    unsigned short* XBhi = WAlo + PW;
    unsigned short* XBlo = XBhi + PX;
    unsigned short* qhi  = XBlo + PX;
    unsigned short* qlo  = qhi + PX;
    unsigned short* khi  = qlo + PX;
    unsigned short* klo  = khi + PX;
    unsigned short* vhi  = klo + PX;
    unsigned short* vlo  = vhi + PX;
    unsigned short* cxhi = vlo + PX;
    unsigned short* cxlo = cxhi + PX;

    // one-time split/convert of W and X into frag-major planes
    prep_kernel<<<dim3(1536), 256, 0, stream>>>(
        wq, wk, wv, wo, x, WAhi, WAlo, XBhi, XBlo);

    // QKV projection: barrier-free MFMA GEMM -> attention planes
    gemm_mfma<<<dim3(384), 256, 0, stream>>>(
        0, WAhi, WAlo, XBhi, XBlo, bq, bk, bv,
        qhi, qlo, khi, klo, vhi, vlo, nullptr);

    // barrier-free MFMA flash attention -> ctx B-operand planes
    attn_mfma<<<dim3(512), 256, 0, stream>>>(
        qhi, qlo, khi, klo, vhi, vlo, ek, ev, cxhi, cxlo);

    // output projection: same GEMM, A=Wo, B=ctx -> natural fp32 out
    gemm_mfma<<<dim3(128), 256, 0, stream>>>(
        1, WAhi, WAlo, cxhi, cxlo, bo, bo, bo,
        nullptr, nullptr, nullptr, nullptr, nullptr, nullptr, out);
}